// Round 5
// baseline (126.710 us; speedup 1.0000x reference)
//
#include <hip/hip_runtime.h>
#include <stdint.h>

#define IN_DIM   4096
#define OUT_DIM  4096
#define TPB      512
#define TOKS     8        // tokens per block; LDS = 4 bf16x2 pairs per column

// pack two fp32 -> bf16x2 dword (lo16 = a, hi16 = b), round-to-nearest-even
__device__ __forceinline__ uint32_t pack_bf16x2(float a, float b) {
    uint32_t ua = __float_as_uint(a);
    uint32_t ub = __float_as_uint(b);
    ua = (ua + 0x7fffu + ((ua >> 16) & 1u)) >> 16;
    ub = (ub + 0x7fffu + ((ub >> 16) & 1u)) & 0xffff0000u;
    return ub | ua;
}

// Stage 8 tokens of x (fp32, [token][IN_DIM]) into LDS as bf16x2, column-major:
// xs[col*4 + pair]; pair p holds tokens (2p, 2p+1).
// Per-lane write rotation keeps staging writes ~2-way banked (free).
__device__ __forceinline__ void stage_x_tile(const float* __restrict__ x,
                                             size_t tb, uint32_t* xs, int tid) {
    const int lane = tid & 63;
    const int wave = tid >> 6;          // 0..7
    const int tp   = lane >> 4;         // token pair 0..3
    const int rot  = (lane >> 1) & 3;   // write-order rotation
    const float* xa = x + (tb + 2 * (size_t)tp) * IN_DIM;
    const float* xb = xa + IN_DIM;
    #pragma unroll
    for (int it = 0; it < IN_DIM / 4 / 128; ++it) {   // 8 iterations
        const int c4 = (lane & 15) + 16 * wave + 128 * it;   // float4 column group
        const float4 a = *reinterpret_cast<const float4*>(xa + 4 * c4);
        const float4 b = *reinterpret_cast<const float4*>(xb + 4 * c4);
        const uint32_t d0 = pack_bf16x2(a.x, b.x);
        const uint32_t d1 = pack_bf16x2(a.y, b.y);
        const uint32_t d2 = pack_bf16x2(a.z, b.z);
        const uint32_t d3 = pack_bf16x2(a.w, b.w);
        // branchless rotate-left by rot (no runtime array indexing -> no scratch)
        const uint32_t t0 = (rot & 2) ? d2 : d0;
        const uint32_t t1 = (rot & 2) ? d3 : d1;
        const uint32_t t2 = (rot & 2) ? d0 : d2;
        const uint32_t t3 = (rot & 2) ? d1 : d3;
        const uint32_t u0 = (rot & 1) ? t1 : t0;
        const uint32_t u1 = (rot & 1) ? t2 : t1;
        const uint32_t u2 = (rot & 1) ? t3 : t2;
        const uint32_t u3 = (rot & 1) ? t0 : t3;
        const int cb = 4 * c4;
        xs[(cb + ((0 + rot) & 3)) * 4 + tp] = u0;
        xs[(cb + ((1 + rot) & 3)) * 4 + tp] = u1;
        xs[(cb + ((2 + rot) & 3)) * 4 + tp] = u2;
        xs[(cb + ((3 + rot) & 3)) * 4 + tp] = u3;
    }
}

// ELL metadata: ell[k*OUT_DIM + r] = (bf16(values) << 16) | col ; zero padded.
// One thread per (r, k) element.
__global__ void build_ell(const float* __restrict__ values,
                          const int* __restrict__ row_offs,
                          const int* __restrict__ col_idx,
                          uint32_t* __restrict__ ell, int kalloc) {
    const int idx = blockIdx.x * blockDim.x + threadIdx.x;
    const int r = idx & (OUT_DIM - 1);
    const int k = idx >> 12;            // log2(OUT_DIM)
    if (k >= kalloc) return;
    const int beg = row_offs[r];
    const int end = row_offs[r + 1];
    uint32_t u = 0;
    if (beg + k < end) {
        const uint32_t c = (uint32_t)col_idx[beg + k];
        uint32_t vb = __float_as_uint(values[beg + k]);
        vb = (vb + 0x7fffu + ((vb >> 16) & 1u)) & 0xffff0000u;
        u = vb | c;
    }
    ell[(size_t)k * OUT_DIM + r] = u;
}

// 8 MACs from one bf16x2-packed uint4 (8 tokens) against value e
// (value used with col bits in mantissa tail: rel err < 2^-11).
#define FMA8(E, D)                                                    \
    do {                                                              \
        const float v_ = __uint_as_float(E);                          \
        acc0 = fmaf(v_, __uint_as_float((D).x << 16), acc0);          \
        acc1 = fmaf(v_, __uint_as_float((D).x & 0xffff0000u), acc1);  \
        acc2 = fmaf(v_, __uint_as_float((D).y << 16), acc2);          \
        acc3 = fmaf(v_, __uint_as_float((D).y & 0xffff0000u), acc3);  \
        acc4 = fmaf(v_, __uint_as_float((D).z << 16), acc4);          \
        acc5 = fmaf(v_, __uint_as_float((D).z & 0xffff0000u), acc5);  \
        acc6 = fmaf(v_, __uint_as_float((D).w << 16), acc6);          \
        acc7 = fmaf(v_, __uint_as_float((D).w & 0xffff0000u), acc7);  \
    } while (0)

#define GATH(D, E) (D) = xs4[(E) & 0xffffu]

__global__ __launch_bounds__(TPB, 4)
void spmm_ell(const float* __restrict__ x, const uint32_t* __restrict__ ell,
              float* __restrict__ y, int ng) {
    __shared__ __align__(16) uint32_t xs[IN_DIM * (TOKS / 2)];   // 64 KB
    const int tid  = threadIdx.x;
    const size_t tb = (size_t)blockIdx.x * TOKS;

    stage_x_tile(x, tb, xs, tid);
    __syncthreads();
    const uint4* xs4 = reinterpret_cast<const uint4*>(xs);

    #pragma unroll 1
    for (int chunk = 0; chunk < OUT_DIM / TPB; ++chunk) {
        const int r = chunk * TPB + tid;
        float acc0 = 0.f, acc1 = 0.f, acc2 = 0.f, acc3 = 0.f;
        float acc4 = 0.f, acc5 = 0.f, acc6 = 0.f, acc7 = 0.f;
        const uint32_t* ep = ell + r;

        // ---- 2-deep software pipeline over k-groups of 4 (ng is even) ----
        // prologue: group0 -> (eA, dA), group1 -> eB
        uint32_t eA0 = ep[0 * (size_t)OUT_DIM], eA1 = ep[1 * (size_t)OUT_DIM];
        uint32_t eA2 = ep[2 * (size_t)OUT_DIM], eA3 = ep[3 * (size_t)OUT_DIM];
        uint4 dA0, dA1, dA2, dA3;
        GATH(dA0, eA0); GATH(dA1, eA1); GATH(dA2, eA2); GATH(dA3, eA3);
        uint32_t eB0 = ep[4 * (size_t)OUT_DIM], eB1 = ep[5 * (size_t)OUT_DIM];
        uint32_t eB2 = ep[6 * (size_t)OUT_DIM], eB3 = ep[7 * (size_t)OUT_DIM];
        uint4 dB0, dB1, dB2, dB3;
        const uint32_t* epn = ep + 8 * (size_t)OUT_DIM;

        #pragma unroll 1
        for (int g = 0; g < ng; g += 2) {
            // step g: compute (eA,dA); gather d for g+1 from eB; prefetch e(g+2)
            const uint32_t tA0 = epn[0 * (size_t)OUT_DIM], tA1 = epn[1 * (size_t)OUT_DIM];
            const uint32_t tA2 = epn[2 * (size_t)OUT_DIM], tA3 = epn[3 * (size_t)OUT_DIM];
            GATH(dB0, eB0); GATH(dB1, eB1); GATH(dB2, eB2); GATH(dB3, eB3);
            FMA8(eA0, dA0); FMA8(eA1, dA1); FMA8(eA2, dA2); FMA8(eA3, dA3);
            epn += 4 * (size_t)OUT_DIM;

            // step g+1: compute (eB,dB); gather d(g+2) from tA; prefetch e(g+3)
            const uint32_t tB0 = epn[0 * (size_t)OUT_DIM], tB1 = epn[1 * (size_t)OUT_DIM];
            const uint32_t tB2 = epn[2 * (size_t)OUT_DIM], tB3 = epn[3 * (size_t)OUT_DIM];
            GATH(dA0, tA0); GATH(dA1, tA1); GATH(dA2, tA2); GATH(dA3, tA3);
            FMA8(eB0, dB0); FMA8(eB1, dB1); FMA8(eB2, dB2); FMA8(eB3, dB3);
            epn += 4 * (size_t)OUT_DIM;

            eA0 = tA0; eA1 = tA1; eA2 = tA2; eA3 = tA3;   // e(g+2), its d in dA
            eB0 = tB0; eB1 = tB1; eB2 = tB2; eB3 = tB3;   // e(g+3)
        }

        y[(tb + 0) * OUT_DIM + r] = acc0;
        y[(tb + 1) * OUT_DIM + r] = acc1;
        y[(tb + 2) * OUT_DIM + r] = acc2;
        y[(tb + 3) * OUT_DIM + r] = acc3;
        y[(tb + 4) * OUT_DIM + r] = acc4;
        y[(tb + 5) * OUT_DIM + r] = acc5;
        y[(tb + 6) * OUT_DIM + r] = acc6;
        y[(tb + 7) * OUT_DIM + r] = acc7;
    }
}

// Fallback if d_ws too small for ELL: direct CSR (fp32 values).
__global__ __launch_bounds__(TPB, 4)
void spmm_csr(const float* __restrict__ x, const float* __restrict__ values,
              const int* __restrict__ row_offs, const int* __restrict__ col_idx,
              float* __restrict__ y) {
    __shared__ __align__(16) uint32_t xs[IN_DIM * (TOKS / 2)];
    const int tid  = threadIdx.x;
    const size_t tb = (size_t)blockIdx.x * TOKS;

    stage_x_tile(x, tb, xs, tid);
    __syncthreads();
    const uint4* xs4 = reinterpret_cast<const uint4*>(xs);

    #pragma unroll 1
    for (int chunk = 0; chunk < OUT_DIM / TPB; ++chunk) {
        const int r = chunk * TPB + tid;
        float acc0 = 0.f, acc1 = 0.f, acc2 = 0.f, acc3 = 0.f;
        float acc4 = 0.f, acc5 = 0.f, acc6 = 0.f, acc7 = 0.f;
        int k = row_offs[r];
        const int ke = row_offs[r + 1];
        for (; k < ke; ++k) {
            const uint32_t e = __float_as_uint(values[k]);
            const uint4 d = xs4[(uint32_t)col_idx[k]];
            FMA8(e, d);
        }
        y[(tb + 0) * OUT_DIM + r] = acc0;
        y[(tb + 1) * OUT_DIM + r] = acc1;
        y[(tb + 2) * OUT_DIM + r] = acc2;
        y[(tb + 3) * OUT_DIM + r] = acc3;
        y[(tb + 4) * OUT_DIM + r] = acc4;
        y[(tb + 5) * OUT_DIM + r] = acc5;
        y[(tb + 6) * OUT_DIM + r] = acc6;
        y[(tb + 7) * OUT_DIM + r] = acc7;
    }
}

extern "C" void kernel_launch(void* const* d_in, const int* in_sizes, int n_in,
                              void* d_out, int out_size, void* d_ws, size_t ws_size,
                              hipStream_t stream) {
    const float* x        = (const float*)d_in[0];
    const float* values   = (const float*)d_in[1];
    const int*   row_offs = (const int*)d_in[2];
    const int*   col_idx  = (const int*)d_in[3];
    float* y = (float*)d_out;

    const int nnz  = in_sizes[1];
    const int rows = in_sizes[2] - 1;              // 4096
    const int ntok = in_sizes[0] / IN_DIM;         // 8192
    const int kmax = nnz / rows + ((nnz % rows) ? 1 : 0);   // 41

    int ng = (kmax + 3) / 4;                       // k-groups of 4
    if (ng & 1) ++ng;                              // even for 2x-unrolled pipeline
    const int kalloc = (ng + 2) * 4;               // +2 zero groups for prefetch

    dim3 grid(ntok / TOKS), block(TPB);
    const size_t ell_bytes = (size_t)kalloc * OUT_DIM * sizeof(uint32_t);
    if (ws_size >= ell_bytes) {
        uint32_t* ell = (uint32_t*)d_ws;
        const int nthr = OUT_DIM * kalloc;
        build_ell<<<dim3((nthr + 255) / 256), dim3(256), 0, stream>>>(
            values, row_offs, col_idx, ell, kalloc);
        spmm_ell<<<grid, block, 0, stream>>>(x, ell, y, ng);
    } else {
        spmm_csr<<<grid, block, 0, stream>>>(x, values, row_offs, col_idx, y);
    }
}

// Round 7
// 112.241 us; speedup vs baseline: 1.1289x; 1.1289x over previous
//
#include <hip/hip_runtime.h>
#include <hip/hip_fp16.h>
#include <stdint.h>

#define IN_DIM   4096
#define OUT_DIM  4096
#define TPB      512
#define TOKS     8        // tokens per block; LDS = 4 f16x2 pairs per column

typedef float  f32x4 __attribute__((ext_vector_type(4)));

// pack two fp32 -> f16x2 dword (lo = a, hi = b) via v_cvt_pkrtz_f16_f32 (1 instr)
__device__ __forceinline__ uint32_t pack_f16x2(float a, float b) {
    auto h = __builtin_amdgcn_cvt_pkrtz(a, b);   // __fp16 ext_vector_type(2)
    uint32_t u;
    __builtin_memcpy(&u, &h, 4);
    return u;
}

// Stage 8 tokens of x (fp32, [token][IN_DIM]) into LDS as f16x2, column-major:
// xs[col*4 + pair]; pair p holds tokens (2p, 2p+1).
// Per-lane write rotation keeps staging writes ~2-way banked (free).
__device__ __forceinline__ void stage_x_tile(const float* __restrict__ x,
                                             size_t tb, uint32_t* xs, int tid) {
    const int lane = tid & 63;
    const int wave = tid >> 6;          // 0..7
    const int tp   = lane >> 4;         // token pair 0..3
    const int rot  = (lane >> 1) & 3;   // write-order rotation
    const float* xa = x + (tb + 2 * (size_t)tp) * IN_DIM;
    const float* xb = xa + IN_DIM;
    #pragma unroll
    for (int it = 0; it < IN_DIM / 4 / 128; ++it) {   // 8 iterations
        const int c4 = (lane & 15) + 16 * wave + 128 * it;   // float4 column group
        const f32x4 a = __builtin_nontemporal_load(
            reinterpret_cast<const f32x4*>(xa + 4 * c4));
        const f32x4 b = __builtin_nontemporal_load(
            reinterpret_cast<const f32x4*>(xb + 4 * c4));
        const uint32_t d0 = pack_f16x2(a[0], b[0]);
        const uint32_t d1 = pack_f16x2(a[1], b[1]);
        const uint32_t d2 = pack_f16x2(a[2], b[2]);
        const uint32_t d3 = pack_f16x2(a[3], b[3]);
        // branchless rotate-left by rot (no runtime array indexing -> no scratch)
        const uint32_t t0 = (rot & 2) ? d2 : d0;
        const uint32_t t1 = (rot & 2) ? d3 : d1;
        const uint32_t t2 = (rot & 2) ? d0 : d2;
        const uint32_t t3 = (rot & 2) ? d1 : d3;
        const uint32_t u0 = (rot & 1) ? t1 : t0;
        const uint32_t u1 = (rot & 1) ? t2 : t1;
        const uint32_t u2 = (rot & 1) ? t3 : t2;
        const uint32_t u3 = (rot & 1) ? t0 : t3;
        const int cb = 4 * c4;
        xs[(cb + ((0 + rot) & 3)) * 4 + tp] = u0;
        xs[(cb + ((1 + rot) & 3)) * 4 + tp] = u1;
        xs[(cb + ((2 + rot) & 3)) * 4 + tp] = u2;
        xs[(cb + ((3 + rot) & 3)) * 4 + tp] = u3;
    }
}

// ELL metadata, group-of-4 interleaved: ell4[g*OUT_DIM + r] = uint4 of entries
// k=4g..4g+3; entry = (bf16(value) << 16) | (col << 4)  (byte address pre-scaled;
// value consumed with col bits as mantissa tail: rel err < 2^-8). Zero padded.
__global__ void build_ell(const float* __restrict__ values,
                          const int* __restrict__ row_offs,
                          const int* __restrict__ col_idx,
                          uint4* __restrict__ ell4, int galloc) {
    const int idx = blockIdx.x * blockDim.x + threadIdx.x;
    const int r = idx & (OUT_DIM - 1);
    const int g = idx >> 12;            // log2(OUT_DIM)
    if (g >= galloc) return;
    const int beg = row_offs[r];
    const int end = row_offs[r + 1];
    uint32_t e0 = 0, e1 = 0, e2 = 0, e3 = 0;
    #pragma unroll
    for (int j = 0; j < 4; ++j) {
        const int k = 4 * g + j;
        uint32_t u = 0;
        if (beg + k < end) {
            const uint32_t c = (uint32_t)col_idx[beg + k];
            uint32_t vb = __float_as_uint(values[beg + k]);
            vb = (vb + 0x7fffu + ((vb >> 16) & 1u)) & 0xffff0000u;
            u = vb | (c << 4);
        }
        if (j == 0) e0 = u; else if (j == 1) e1 = u; else if (j == 2) e2 = u; else e3 = u;
    }
    ell4[(size_t)g * OUT_DIM + r] = make_uint4(e0, e1, e2, e3);
}

// 8 MACs from one f16x2-packed uint4 (8 tokens) against value E.
// fmaf((float)f16, f32, f32) folds to v_fma_mix_f32 (no unpack shifts).
#define FMA8(E, D)                                                   \
    do {                                                             \
        const float v_ = __uint_as_float(E);                         \
        const __half2* h_ = reinterpret_cast<const __half2*>(&(D));  \
        acc0 = fmaf(__low2float(h_[0]),  v_, acc0);                  \
        acc1 = fmaf(__high2float(h_[0]), v_, acc1);                  \
        acc2 = fmaf(__low2float(h_[1]),  v_, acc2);                  \
        acc3 = fmaf(__high2float(h_[1]), v_, acc3);                  \
        acc4 = fmaf(__low2float(h_[2]),  v_, acc4);                  \
        acc5 = fmaf(__high2float(h_[2]), v_, acc5);                  \
        acc6 = fmaf(__low2float(h_[3]),  v_, acc6);                  \
        acc7 = fmaf(__high2float(h_[3]), v_, acc7);                  \
    } while (0)

// gather: entry's low bits are already the byte offset (col<<4)
#define GATH(D, E)                                                           \
    (D) = *reinterpret_cast<const uint4*>(reinterpret_cast<const char*>(xs) + \
                                          ((E) & 0xfff0u))

__global__ __launch_bounds__(TPB, 4)
void spmm_ell(const float* __restrict__ x, const uint4* __restrict__ ell4,
              float* __restrict__ y, int ng) {   // ng is ODD
    __shared__ __align__(16) uint32_t xs[IN_DIM * (TOKS / 2)];   // 64 KB
    const int tid  = threadIdx.x;
    const size_t tb = (size_t)blockIdx.x * TOKS;

    stage_x_tile(x, tb, xs, tid);
    __syncthreads();

    #pragma unroll 1
    for (int chunk = 0; chunk < OUT_DIM / TPB; ++chunk) {
        const int r = chunk * TPB + tid;
        float acc0 = 0.f, acc1 = 0.f, acc2 = 0.f, acc3 = 0.f;
        float acc4 = 0.f, acc5 = 0.f, acc6 = 0.f, acc7 = 0.f;
        const uint4* ep = ell4 + r;

        // ---- 2-deep software pipeline over k-groups of 4 ----
        uint4 eA = ep[0];                           // group 0
        uint4 dA0, dA1, dA2, dA3;
        GATH(dA0, eA.x); GATH(dA1, eA.y); GATH(dA2, eA.z); GATH(dA3, eA.w);
        uint4 eB = ep[OUT_DIM];                     // group 1
        uint4 dB0, dB1, dB2, dB3;
        const uint4* epn = ep + 2 * (size_t)OUT_DIM;

        #pragma unroll 1
        for (int g = 0; g + 2 < ng; g += 2) {
            // step g: compute (eA,dA); gather g+1 from eB; prefetch e(g+2)
            const uint4 tA = epn[0];
            GATH(dB0, eB.x); GATH(dB1, eB.y); GATH(dB2, eB.z); GATH(dB3, eB.w);
            FMA8(eA.x, dA0); FMA8(eA.y, dA1); FMA8(eA.z, dA2); FMA8(eA.w, dA3);
            // step g+1: compute (eB,dB); gather g+2 from tA; prefetch e(g+3)
            const uint4 tB = epn[OUT_DIM];
            GATH(dA0, tA.x); GATH(dA1, tA.y); GATH(dA2, tA.z); GATH(dA3, tA.w);
            FMA8(eB.x, dB0); FMA8(eB.y, dB1); FMA8(eB.z, dB2); FMA8(eB.w, dB3);
            eA = tA; eB = tB;
            epn += 2 * (size_t)OUT_DIM;
        }
        // epilogue: last (odd) group already gathered in (eA, dA)
        FMA8(eA.x, dA0); FMA8(eA.y, dA1); FMA8(eA.z, dA2); FMA8(eA.w, dA3);

        __builtin_nontemporal_store(acc0, &y[(tb + 0) * OUT_DIM + r]);
        __builtin_nontemporal_store(acc1, &y[(tb + 1) * OUT_DIM + r]);
        __builtin_nontemporal_store(acc2, &y[(tb + 2) * OUT_DIM + r]);
        __builtin_nontemporal_store(acc3, &y[(tb + 3) * OUT_DIM + r]);
        __builtin_nontemporal_store(acc4, &y[(tb + 4) * OUT_DIM + r]);
        __builtin_nontemporal_store(acc5, &y[(tb + 5) * OUT_DIM + r]);
        __builtin_nontemporal_store(acc6, &y[(tb + 6) * OUT_DIM + r]);
        __builtin_nontemporal_store(acc7, &y[(tb + 7) * OUT_DIM + r]);
    }
}

// Fallback if d_ws too small for ELL: direct CSR (fp32 values, f16 tokens).
__global__ __launch_bounds__(TPB, 4)
void spmm_csr(const float* __restrict__ x, const float* __restrict__ values,
              const int* __restrict__ row_offs, const int* __restrict__ col_idx,
              float* __restrict__ y) {
    __shared__ __align__(16) uint32_t xs[IN_DIM * (TOKS / 2)];
    const int tid  = threadIdx.x;
    const size_t tb = (size_t)blockIdx.x * TOKS;

    stage_x_tile(x, tb, xs, tid);
    __syncthreads();

    #pragma unroll 1
    for (int chunk = 0; chunk < OUT_DIM / TPB; ++chunk) {
        const int r = chunk * TPB + tid;
        float acc0 = 0.f, acc1 = 0.f, acc2 = 0.f, acc3 = 0.f;
        float acc4 = 0.f, acc5 = 0.f, acc6 = 0.f, acc7 = 0.f;
        int k = row_offs[r];
        const int ke = row_offs[r + 1];
        for (; k < ke; ++k) {
            const uint32_t e = __float_as_uint(values[k]);
            const uint32_t off = (uint32_t)col_idx[k] << 4;
            uint4 d;
            GATH(d, off);
            FMA8(e, d);
        }
        y[(tb + 0) * OUT_DIM + r] = acc0;
        y[(tb + 1) * OUT_DIM + r] = acc1;
        y[(tb + 2) * OUT_DIM + r] = acc2;
        y[(tb + 3) * OUT_DIM + r] = acc3;
        y[(tb + 4) * OUT_DIM + r] = acc4;
        y[(tb + 5) * OUT_DIM + r] = acc5;
        y[(tb + 6) * OUT_DIM + r] = acc6;
        y[(tb + 7) * OUT_DIM + r] = acc7;
    }
}

extern "C" void kernel_launch(void* const* d_in, const int* in_sizes, int n_in,
                              void* d_out, int out_size, void* d_ws, size_t ws_size,
                              hipStream_t stream) {
    const float* x        = (const float*)d_in[0];
    const float* values   = (const float*)d_in[1];
    const int*   row_offs = (const int*)d_in[2];
    const int*   col_idx  = (const int*)d_in[3];
    float* y = (float*)d_out;

    const int nnz  = in_sizes[1];
    const int rows = in_sizes[2] - 1;              // 4096
    const int ntok = in_sizes[0] / IN_DIM;         // 8192
    const int kmax = nnz / rows + ((nnz % rows) ? 1 : 0);   // 41

    int ng = (kmax + 3) / 4;                       // k-groups of 4 (11 for kmax=41)
    if (!(ng & 1)) ++ng;                           // pipeline needs ODD ng
    const int galloc = ng + 1;                     // +1 zero group for e-prefetch

    dim3 grid(ntok / TOKS), block(TPB);
    const size_t ell_bytes = (size_t)galloc * OUT_DIM * sizeof(uint4);
    if (ws_size >= ell_bytes) {
        uint4* ell4 = (uint4*)d_ws;
        const int nthr = OUT_DIM * galloc;
        build_ell<<<dim3((nthr + 255) / 256), dim3(256), 0, stream>>>(
            values, row_offs, col_idx, ell4, galloc);
        spmm_ell<<<grid, block, 0, stream>>>(x, ell4, y, ng);
    } else {
        spmm_csr<<<grid, block, 0, stream>>>(x, values, row_offs, col_idx, y);
    }
}